// Round 5
// baseline (691.612 us; speedup 1.0000x reference)
//
#include <hip/hip_runtime.h>

#define N_NODES 100000
#define N_EDGES 1200000
#define DIM 64
#define N_GRAPHS 128
#define N_LAYERS 5

#define NBUCKETS 782          // ceil(100000/128)
#define BCAP 2048             // per-bucket capacity (mean 1534, +13 sigma)
#define CHUNK 8192            // edges per bin block

#define POOL_CH 196
#define POOL_BLOCKS ((N_NODES + POOL_CH - 1) / POOL_CH)

#define ZSTRIDE 68            // 128-row z tile stride; (4*row+dim)%32 spreads banks

typedef unsigned short ushort_t;
typedef unsigned int uint_t;

__device__ __forceinline__ float bf2f(uint_t s) {
  return __uint_as_float(s << 16);
}
__device__ __forceinline__ ushort_t f2bf(float f) {
  uint_t u = __float_as_uint(f);
  uint_t r = u + 0x7fffu + ((u >> 16) & 1u);   // RNE
  return (ushort_t)(r >> 16);
}
__device__ __forceinline__ uint_t pack2(float a, float b) {
  return (uint_t)f2bf(a) | ((uint_t)f2bf(b) << 16);
}

// ---------------- fp32 -> bf16 convert (x only, once) ----------------

__global__ __launch_bounds__(256) void conv_kernel(const float* __restrict__ x,
                                                   ushort_t* __restrict__ xb) {
  int i = blockIdx.x * 256 + threadIdx.x;
  int base = i * 8;
  if (base >= N_NODES * DIM) return;
  float4 a = *(const float4*)(x + base);
  float4 b = *(const float4*)(x + base + 4);
  uint4 o;
  o.x = pack2(a.x, a.y);
  o.y = pack2(a.z, a.w);
  o.z = pack2(b.x, b.y);
  o.w = pack2(b.z, b.w);
  *(uint4*)(xb + base) = o;
}

// ---------------- CSR build stage 1: LDS multisplit into 782 buckets ----------------

__global__ __launch_bounds__(256) void bin_kernel(const int* __restrict__ src,
                                                  const int* __restrict__ dst,
                                                  int* __restrict__ gCursor,
                                                  uint_t* __restrict__ gPairs) {
  __shared__ int hist[NBUCKETS];
  __shared__ int lstart[NBUCKETS];
  __shared__ int lcur[NBUCKETS];
  __shared__ int gbase[NBUCKETS];
  __shared__ uint_t pairbuf[CHUNK];
  __shared__ ushort_t bidbuf[CHUNK];
  __shared__ int wsum[4];

  const int t = threadIdx.x;
  const int e0 = blockIdx.x * CHUNK;
  const int ecnt = min(CHUNK, N_EDGES - e0);

  for (int i = t; i < NBUCKETS; i += 256) hist[i] = 0;
  __syncthreads();

  for (int i = t; i < ecnt; i += 256) {
    int d = dst[e0 + i];
    atomicAdd(&hist[d >> 7], 1);
  }
  __syncthreads();

  const int base4 = t * 4;
  int h0 = 0, h1 = 0, h2 = 0, h3 = 0;
  if (base4 + 0 < NBUCKETS) h0 = hist[base4 + 0];
  if (base4 + 1 < NBUCKETS) h1 = hist[base4 + 1];
  if (base4 + 2 < NBUCKETS) h2 = hist[base4 + 2];
  if (base4 + 3 < NBUCKETS) h3 = hist[base4 + 3];
  int tsum = h0 + h1 + h2 + h3;
  int lane = t & 63, wid = t >> 6;
  int inc = tsum;
  #pragma unroll
  for (int off = 1; off < 64; off <<= 1) {
    int v = __shfl_up(inc, off);
    if (lane >= off) inc += v;
  }
  if (lane == 63) wsum[wid] = inc;
  __syncthreads();
  int wadd = 0;
  for (int w = 0; w < wid; ++w) wadd += wsum[w];
  int ex = wadd + inc - tsum;
  if (base4 + 0 < NBUCKETS) { lstart[base4 + 0] = ex; lcur[base4 + 0] = ex; } ex += h0;
  if (base4 + 1 < NBUCKETS) { lstart[base4 + 1] = ex; lcur[base4 + 1] = ex; } ex += h1;
  if (base4 + 2 < NBUCKETS) { lstart[base4 + 2] = ex; lcur[base4 + 2] = ex; } ex += h2;
  if (base4 + 3 < NBUCKETS) { lstart[base4 + 3] = ex; lcur[base4 + 3] = ex; }
  __syncthreads();

  for (int i = t; i < ecnt; i += 256) {
    int s = src[e0 + i];
    int d = dst[e0 + i];
    int b = d >> 7;
    int p = atomicAdd(&lcur[b], 1);
    pairbuf[p] = (uint_t)s | ((uint_t)(d & 127) << 17);
    bidbuf[p] = (ushort_t)b;
  }
  __syncthreads();

  for (int b = t; b < NBUCKETS; b += 256) {
    int cnt = lcur[b] - lstart[b];
    gbase[b] = cnt ? atomicAdd(&gCursor[b], cnt) : 0;
  }
  __syncthreads();

  for (int i = t; i < ecnt; i += 256) {
    int b = bidbuf[i];
    int pos = gbase[b] + (i - lstart[b]);
    if (pos < BCAP) gPairs[b * BCAP + pos] = pairbuf[i];
  }
}

__global__ __launch_bounds__(1024) void bscan_kernel(const int* __restrict__ gCursor,
                                                     int* __restrict__ bucketBase) {
  __shared__ int sm[1024];
  int t = threadIdx.x;
  int v = (t < NBUCKETS) ? min(gCursor[t], BCAP) : 0;
  sm[t] = v;
  __syncthreads();
  for (int off = 1; off < 1024; off <<= 1) {
    int x = (t >= off) ? sm[t - off] : 0;
    __syncthreads();
    sm[t] += x;
    __syncthreads();
  }
  bucketBase[t] = sm[t] - v;
  if (t == NBUCKETS - 1) bucketBase[NBUCKETS] = sm[t];
}

// ---------------- stage 2: per-bucket sort by (srcPart, dstLocal) ----------------
// emits binrp[b][1025] (absolute edge offsets per (part,node) run) + compact sEdges.

__global__ __launch_bounds__(256) void csort_kernel(const int* __restrict__ gCursor,
                                                    const int* __restrict__ bucketBase,
                                                    const uint_t* __restrict__ gPairs,
                                                    int* __restrict__ binrp,
                                                    int* __restrict__ sEdges) {
  __shared__ uint_t vals[BCAP];
  __shared__ int hist[1024];
  __shared__ int cur[1024];
  __shared__ int wsum[4];

  const int b = blockIdx.x, t = threadIdx.x;
  const int cnt = min(gCursor[b], BCAP);
  const int base = bucketBase[b];

  for (int i = t; i < 1024; i += 256) hist[i] = 0;
  __syncthreads();
  for (int i = t; i < cnt; i += 256) {
    uint_t v = gPairs[b * BCAP + i];
    vals[i] = v;
    int bin = (int)((v & 0x1FFFFu) >> 14) * 128 + (int)((v >> 17) & 127);
    atomicAdd(&hist[bin], 1);
  }
  __syncthreads();

  // exclusive scan over 1024 bins (4 per thread)
  const int b4 = t * 4;
  int h0 = hist[b4], h1 = hist[b4 + 1], h2 = hist[b4 + 2], h3 = hist[b4 + 3];
  int tsum = h0 + h1 + h2 + h3;
  int lane = t & 63, wid = t >> 6;
  int inc = tsum;
  #pragma unroll
  for (int off = 1; off < 64; off <<= 1) {
    int v = __shfl_up(inc, off);
    if (lane >= off) inc += v;
  }
  if (lane == 63) wsum[wid] = inc;
  __syncthreads();
  int wadd = 0;
  for (int w = 0; w < wid; ++w) wadd += wsum[w];
  int ex = wadd + inc - tsum;
  cur[b4 + 0] = ex; binrp[b * 1025 + b4 + 0] = base + ex; ex += h0;
  cur[b4 + 1] = ex; binrp[b * 1025 + b4 + 1] = base + ex; ex += h1;
  cur[b4 + 2] = ex; binrp[b * 1025 + b4 + 2] = base + ex; ex += h2;
  cur[b4 + 3] = ex; binrp[b * 1025 + b4 + 3] = base + ex;
  if (t == 255) binrp[b * 1025 + 1024] = base + cnt;
  __syncthreads();

  for (int i = t; i < cnt; i += 256) {
    uint_t v = vals[i];
    int bin = (int)((v & 0x1FFFFu) >> 14) * 128 + (int)((v >> 17) & 127);
    int p = atomicAdd(&cur[bin], 1);
    sEdges[base + p] = (int)(v & 0x1FFFFu);
  }
}

// ---------------- fused layer: agg (part-phased gather) + MLP ----------------
// block = 128-node bucket. Phase A: lane (sub=node-of-8, m=dim-group) accumulates
// its node's 8 dims over part-major edge runs -> zs in LDS. Phase B: 2x matmul.

__global__ __launch_bounds__(256) void layer_kernel(const ushort_t* __restrict__ h,
                                                    ushort_t* __restrict__ hout,
                                                    const int* __restrict__ binrp,
                                                    const int* __restrict__ sEdges,
                                                    const float* __restrict__ W1,
                                                    const float* __restrict__ b1,
                                                    const float* __restrict__ gam,
                                                    const float* __restrict__ bet,
                                                    const float* __restrict__ W2,
                                                    const float* __restrict__ b2) {
  __shared__ float zs[128 * ZSTRIDE];
  __shared__ float wls[4096];          // W staging; aliased as rpl during phase A
  int* rpl = (int*)wls;

  const int t = threadIdx.x;
  const int b = blockIdx.x;
  const int base = b * 128;
  const int w = t >> 6, l = t & 63;
  const int sub = l >> 3;              // node within group of 8
  const int dm = l & 7;                // dim group
  const int dp = dm << 3;              // dim base 0..56

  for (int i = t; i < 1025; i += 256) rpl[i] = binrp[b * 1025 + i];
  __syncthreads();

  #pragma unroll 1
  for (int r = 0; r < 4; ++r) {
    int nl = (r << 5) | (w << 3) | sub;
    int node = base + nl;
    float a[8];
    #pragma unroll
    for (int q = 0; q < 8; ++q) a[q] = 0.f;
    if (node < N_NODES) {
      uint4 rr = *(const uint4*)(h + (size_t)node * DIM + dp);
      a[0] = bf2f(rr.x & 0xffffu); a[1] = bf2f(rr.x >> 16);
      a[2] = bf2f(rr.y & 0xffffu); a[3] = bf2f(rr.y >> 16);
      a[4] = bf2f(rr.z & 0xffffu); a[5] = bf2f(rr.z >> 16);
      a[6] = bf2f(rr.w & 0xffffu); a[7] = bf2f(rr.w >> 16);
      #pragma unroll 1
      for (int p = 0; p < 7; ++p) {          // srcPart = src>>14 in 0..6
        int idx0 = (p << 7) | nl;
        int s = rpl[idx0];
        int e = rpl[idx0 + 1];
        int j = s;
        for (; j + 2 <= e; j += 2) {
          int u0 = sEdges[j], u1 = sEdges[j + 1];
          uint4 r0 = *(const uint4*)(h + (size_t)u0 * DIM + dp);
          uint4 r1 = *(const uint4*)(h + (size_t)u1 * DIM + dp);
          a[0] += bf2f(r0.x & 0xffffu) + bf2f(r1.x & 0xffffu);
          a[1] += bf2f(r0.x >> 16)     + bf2f(r1.x >> 16);
          a[2] += bf2f(r0.y & 0xffffu) + bf2f(r1.y & 0xffffu);
          a[3] += bf2f(r0.y >> 16)     + bf2f(r1.y >> 16);
          a[4] += bf2f(r0.z & 0xffffu) + bf2f(r1.z & 0xffffu);
          a[5] += bf2f(r0.z >> 16)     + bf2f(r1.z >> 16);
          a[6] += bf2f(r0.w & 0xffffu) + bf2f(r1.w & 0xffffu);
          a[7] += bf2f(r0.w >> 16)     + bf2f(r1.w >> 16);
        }
        if (j < e) {
          int u0 = sEdges[j];
          uint4 r0 = *(const uint4*)(h + (size_t)u0 * DIM + dp);
          a[0] += bf2f(r0.x & 0xffffu);
          a[1] += bf2f(r0.x >> 16);
          a[2] += bf2f(r0.y & 0xffffu);
          a[3] += bf2f(r0.y >> 16);
          a[4] += bf2f(r0.z & 0xffffu);
          a[5] += bf2f(r0.z >> 16);
          a[6] += bf2f(r0.w & 0xffffu);
          a[7] += bf2f(r0.w >> 16);
        }
      }
    }
    *(float4*)(zs + nl * ZSTRIDE + dp)     = make_float4(a[0], a[1], a[2], a[3]);
    *(float4*)(zs + nl * ZSTRIDE + dp + 4) = make_float4(a[4], a[5], a[6], a[7]);
  }
  __syncthreads();   // phase A done; rpl dead

  // ---- phase B: MLP with 256 threads: thread -> 4 nodes x 8 dims ----
  #pragma unroll
  for (int i = 0; i < 4; ++i) {
    int f = (i * 256 + t) * 4;
    *(float4*)(wls + f) = *(const float4*)(W1 + f);
  }
  __syncthreads();

  const int m = t & 7;
  const int gq = t >> 3;               // 0..31
  const int c0 = m * 8;

  float acc[4][8];
  #pragma unroll
  for (int j = 0; j < 4; ++j)
    #pragma unroll
    for (int i = 0; i < 8; ++i) acc[j][i] = 0.f;

  #pragma unroll 2
  for (int k0 = 0; k0 < 64; k0 += 4) {
    float zv[4][4];
    #pragma unroll
    for (int j = 0; j < 4; ++j)
      *(float4*)zv[j] = *(const float4*)(zs + (gq + 32 * j) * ZSTRIDE + k0);
    #pragma unroll
    for (int kk = 0; kk < 4; ++kk) {
      float wa[8];
      *(float4*)&wa[0] = *(const float4*)(wls + (k0 + kk) * 64 + c0);
      *(float4*)&wa[4] = *(const float4*)(wls + (k0 + kk) * 64 + c0 + 4);
      #pragma unroll
      for (int j = 0; j < 4; ++j) {
        float zz = zv[j][kk];
        #pragma unroll
        for (int i = 0; i < 8; ++i) acc[j][i] = fmaf(zz, wa[i], acc[j][i]);
      }
    }
  }

  const float BNR = 0.99999500003749971893f;   // 1/sqrt(1+1e-5)
  float s_[8], o_[8];
  #pragma unroll
  for (int i = 0; i < 8; ++i) {
    float sc = gam[c0 + i] * BNR;
    s_[i] = sc;
    o_[i] = fmaf(b1[c0 + i], sc, bet[c0 + i]);
  }
  #pragma unroll
  for (int j = 0; j < 4; ++j)
    #pragma unroll
    for (int i = 0; i < 8; ++i) {
      float v = fmaf(acc[j][i], s_[i], o_[i]);
      acc[j][i] = v > 0.f ? v : 0.f;
    }

  __syncthreads();   // matmul1 zs reads done

  #pragma unroll
  for (int j = 0; j < 4; ++j) {
    int n = gq + 32 * j;
    *(float4*)(zs + n * ZSTRIDE + c0)     = make_float4(acc[j][0], acc[j][1], acc[j][2], acc[j][3]);
    *(float4*)(zs + n * ZSTRIDE + c0 + 4) = make_float4(acc[j][4], acc[j][5], acc[j][6], acc[j][7]);
  }
  #pragma unroll
  for (int i = 0; i < 4; ++i) {
    int f = (i * 256 + t) * 4;
    *(float4*)(wls + f) = *(const float4*)(W2 + f);
  }
  __syncthreads();

  float acc2[4][8];
  #pragma unroll
  for (int j = 0; j < 4; ++j)
    #pragma unroll
    for (int i = 0; i < 8; ++i) acc2[j][i] = 0.f;

  #pragma unroll 2
  for (int k0 = 0; k0 < 64; k0 += 4) {
    float zv[4][4];
    #pragma unroll
    for (int j = 0; j < 4; ++j)
      *(float4*)zv[j] = *(const float4*)(zs + (gq + 32 * j) * ZSTRIDE + k0);
    #pragma unroll
    for (int kk = 0; kk < 4; ++kk) {
      float wa[8];
      *(float4*)&wa[0] = *(const float4*)(wls + (k0 + kk) * 64 + c0);
      *(float4*)&wa[4] = *(const float4*)(wls + (k0 + kk) * 64 + c0 + 4);
      #pragma unroll
      for (int j = 0; j < 4; ++j) {
        float zz = zv[j][kk];
        #pragma unroll
        for (int i = 0; i < 8; ++i) acc2[j][i] = fmaf(zz, wa[i], acc2[j][i]);
      }
    }
  }

  float bb[8];
  #pragma unroll
  for (int i = 0; i < 8; ++i) bb[i] = b2[c0 + i];
  #pragma unroll
  for (int j = 0; j < 4; ++j) {
    int gn = base + gq + 32 * j;
    if (gn < N_NODES) {
      uint4 o;
      float v0 = fmaxf(acc2[j][0] + bb[0], 0.f);
      float v1 = fmaxf(acc2[j][1] + bb[1], 0.f);
      float v2 = fmaxf(acc2[j][2] + bb[2], 0.f);
      float v3 = fmaxf(acc2[j][3] + bb[3], 0.f);
      float v4 = fmaxf(acc2[j][4] + bb[4], 0.f);
      float v5 = fmaxf(acc2[j][5] + bb[5], 0.f);
      float v6 = fmaxf(acc2[j][6] + bb[6], 0.f);
      float v7 = fmaxf(acc2[j][7] + bb[7], 0.f);
      o.x = pack2(v0, v1);
      o.y = pack2(v2, v3);
      o.z = pack2(v4, v5);
      o.w = pack2(v6, v7);
      *(uint4*)(hout + (size_t)gn * DIM + c0) = o;
    }
  }
}

// ---------------- pool: partial sums (batch sorted) + tiny head ----------------

__global__ __launch_bounds__(256) void pool_partial_kernel(const ushort_t* __restrict__ h,
                                                           const int* __restrict__ batch,
                                                           float* __restrict__ pooled) {
  int r0 = blockIdx.x * POOL_CH;
  int rend = min(r0 + POOL_CH, N_NODES);
  int w = threadIdx.x >> 6, d = threadIdx.x & 63;
  float acc = 0.f;
  int curg = -1;
  for (int i = r0 + w; i < rend; i += 4) {
    int g = batch[i];
    if (g != curg) {
      if (curg >= 0) atomicAdd(&pooled[curg * DIM + d], acc);
      acc = 0.f;
      curg = g;
    }
    acc += bf2f((uint_t)h[i * DIM + d]);
  }
  if (curg >= 0) atomicAdd(&pooled[curg * DIM + d], acc);
}

__global__ __launch_bounds__(256) void head_kernel(const float* __restrict__ pooled,
                                                   const float* __restrict__ lw,
                                                   const float* __restrict__ lb,
                                                   float* __restrict__ out) {
  int idx = blockIdx.x * 256 + threadIdx.x;
  if (idx >= N_GRAPHS * DIM) return;
  int g = idx >> 6, d = idx & 63;
  float o = lb[d];
  #pragma unroll 8
  for (int k = 0; k < 64; ++k) o = fmaf(pooled[g * 64 + k], lw[k * 64 + d], o);
  out[idx] = fmaxf(o, 0.f);
}

// ---------------- host ----------------

extern "C" void kernel_launch(void* const* d_in, const int* in_sizes, int n_in,
                              void* d_out, int out_size, void* d_ws, size_t ws_size,
                              hipStream_t stream) {
  const float* x      = (const float*)d_in[0];
  const int*   ei     = (const int*)d_in[1];
  const int*   srcp   = ei;
  const int*   dstp   = ei + N_EDGES;
  const int*   batch  = (const int*)d_in[2];
  const float* W1s    = (const float*)d_in[3];
  const float* b1s    = (const float*)d_in[4];
  const float* gammas = (const float*)d_in[5];
  const float* betas  = (const float*)d_in[6];
  const float* W2s    = (const float*)d_in[7];
  const float* b2s    = (const float*)d_in[8];
  const float* lin1_w = (const float*)d_in[9];
  const float* lin1_b = (const float*)d_in[10];

  char* p = (char*)d_ws;
  ushort_t* xb     = (ushort_t*)p; p += (size_t)N_NODES * DIM * 2;      // 12.8 MB
  ushort_t* h1     = (ushort_t*)p; p += (size_t)N_NODES * DIM * 2;      // 12.8 MB
  uint_t*   gPairs = (uint_t*)p;   p += (size_t)NBUCKETS * BCAP * 4;    // 6.4 MB
  int*      sEdges = (int*)p;      p += (size_t)N_EDGES * 4;            // 4.8 MB
  int*      binrp  = (int*)p;      p += 3206208;                        // 782*1025*4 padded
  int*      gCursor    = (int*)p;  p += 4096;
  int*      bucketBase = (int*)p;  p += 4096;
  float*    pooled     = (float*)p;

  hipMemsetAsync(gCursor, 0, 1024 * sizeof(int), stream);
  hipMemsetAsync(pooled, 0, N_GRAPHS * DIM * sizeof(float), stream);
  conv_kernel<<<(N_NODES * DIM / 8 + 255) / 256, 256, 0, stream>>>(x, xb);

  const int BIN_BLOCKS = (N_EDGES + CHUNK - 1) / CHUNK;   // 147
  bin_kernel<<<BIN_BLOCKS, 256, 0, stream>>>(srcp, dstp, gCursor, gPairs);
  bscan_kernel<<<1, 1024, 0, stream>>>(gCursor, bucketBase);
  csort_kernel<<<NBUCKETS, 256, 0, stream>>>(gCursor, bucketBase, gPairs, binrp, sEdges);

  const ushort_t* hin = xb;
  for (int l = 0; l < N_LAYERS; ++l) {
    ushort_t* hout = (l & 1) ? xb : h1;
    layer_kernel<<<NBUCKETS, 256, 0, stream>>>(hin, hout, binrp, sEdges,
        W1s + (size_t)l * DIM * DIM, b1s + (size_t)l * DIM,
        gammas + (size_t)l * DIM, betas + (size_t)l * DIM,
        W2s + (size_t)l * DIM * DIM, b2s + (size_t)l * DIM);
    hin = hout;
  }

  pool_partial_kernel<<<POOL_BLOCKS, 256, 0, stream>>>(h1, batch, pooled);
  head_kernel<<<(N_GRAPHS * DIM + 255) / 256, 256, 0, stream>>>(pooled, lin1_w, lin1_b, (float*)d_out);
}